// Round 8
// baseline (152.016 us; speedup 1.0000x reference)
//
#include <hip/hip_runtime.h>

// Bilateral filter, fixed shape: x[16,3,512,512] fp32, K=5, pad=2 reflect.
// sigma_color = sigma_space = 1.1; both normalizations cancel in the ratio.
// w = exp2(coef2*d^2 + coef2*s2), coef2 = -log2(e)/2.42; coef2*s2 is a
// compile-time constant per offset. Center tap: w=1 -> free init.
//
// R7 model revision: kernel is ISSUE-bound (pins/sched_barrier gave 0 delta;
// VGPR stuck at 52). pk_f32 is half-rate on gfx950 (157.3 TF spec = unpacked
// rate) and shifted-window pk operands force v_mov marshaling -> packing was
// ~neutral. This round cuts instructions instead:
//  - scalar f32 tap math (no pair marshaling)
//  - pair symmetry: w(a->b)==w(b->a). 12 half-space offsets; in-tile pairs
//    (90/thread) compute one exp for two taps; one-sided taps (294-90 exps
//    total, -26.5%) cover partners outside the 4x4 tile; boundary loop adds
//    the -o taps whose pair-partner a-o falls outside the tile.
//    Each output gets exactly 24 non-center taps, each once (enumerated).
//    In-tile pixels are real (unreflected) so sharing is exact.
//
// Column reflect via 2 cndmask fixups per row (verified R2-R7):
//   w0==0  : col -2 -> x[2]  = c4.z ;  w0==508: col 513 -> x[509] = c4.y
// Row reflect: r = min(abs(r), 2*(H-1)-r).

constexpr int H_ = 512;
constexpr int W_ = 512;

__global__ __launch_bounds__(256, 3) void bilateral_kernel(
    const float* __restrict__ x,
    float* __restrict__ out,
    int nthreads)
{
    int t = blockIdx.x * 256 + threadIdx.x;
    if (t >= nthreads) return;

    int qx = t & 127;          // tile col index (4-wide tiles)
    int rg = (t >> 7) & 127;   // tile row index (4-tall tiles)
    int pl = t >> 14;          // plane (b*C + c)
    int w0 = qx << 2;
    int h0 = rg << 2;
    const float* plane = x + ((long)pl << 18);   // 512*512
    float* oplane = out + ((long)pl << 18);

    int aL = max(w0 - 2, 0);
    int aR = min(w0 + 4, W_ - 2);
    bool bL = (w0 == 0);
    bool bR = (w0 == W_ - 4);

    // Load full 8x8 window (rows h0-2..h0+5, cols w0-2..w0+5).
    float Wn[8][8];
#pragma unroll
    for (int k = 0; k < 8; ++k) {
        int r = h0 + k - 2;
        r = min(abs(r), 2 * (H_ - 1) - r);
        const float* rp = plane + r * W_;
        float2 l2 = *(const float2*)(rp + aL);
        float4 c4 = *(const float4*)(rp + w0);
        float2 r2 = *(const float2*)(rp + aR);
        Wn[k][2] = c4.x; Wn[k][3] = c4.y; Wn[k][4] = c4.z; Wn[k][5] = c4.w;
        Wn[k][0] = bL ? c4.z : l2.x;   // reflect col -2 -> +2
        Wn[k][1] = l2.y;
        Wn[k][6] = r2.x;
        Wn[k][7] = bR ? c4.y : r2.y;   // reflect col 513 -> 509
    }

    // Pin window elements into VGPRs (R5 win; harmless since, keep).
#pragma unroll
    for (int k = 0; k < 8; ++k)
#pragma unroll
        for (int j = 0; j < 8; ++j)
            asm volatile("" : "+v"(Wn[k][j]));
    __builtin_amdgcn_sched_barrier(0);

    const float coef2 = -0.59615498f;  // -log2(e)/(2*1.21)

    // Center taps are free: w = exp2(0) = 1.
    float num[4][4], den[4][4];
#pragma unroll
    for (int ai = 0; ai < 4; ++ai)
#pragma unroll
        for (int aj = 0; aj < 4; ++aj) {
            num[ai][aj] = Wn[ai + 2][aj + 2];
            den[ai][aj] = 1.0f;
        }

    // Half-space offsets: (di>0) or (di==0 && dj>0).
#pragma unroll
    for (int di = 0; di <= 2; ++di) {
#pragma unroll
        for (int dj = -2; dj <= 2; ++dj) {
            if (di == 0 && dj <= 0) continue;          // compile-time prune
            const float cs = coef2 * (float)(di * di + dj * dj);

            // Main loop: a's +o tap; shared with b = a+o when b in tile.
#pragma unroll
            for (int ai = 0; ai < 4; ++ai) {
#pragma unroll
                for (int aj = 0; aj < 4; ++aj) {
                    float pa = Wn[ai + 2][aj + 2];
                    float pb = Wn[ai + 2 + di][aj + 2 + dj];
                    float d = pb - pa;
                    float w = __builtin_amdgcn_exp2f(fmaf(d * coef2, d, cs));
                    num[ai][aj] = fmaf(w, pb, num[ai][aj]);
                    den[ai][aj] += w;
                    if (ai + di <= 3 && aj + dj >= 0 && aj + dj <= 3) {
                        num[ai + di][aj + dj] =
                            fmaf(w, pa, num[ai + di][aj + dj]);
                        den[ai + di][aj + dj] += w;
                    }
                }
            }
            // Boundary loop: a's -o tap when partner a-o is outside the tile
            // (otherwise it was covered by the pair-part above).
#pragma unroll
            for (int ai = 0; ai < 4; ++ai) {
#pragma unroll
                for (int aj = 0; aj < 4; ++aj) {
                    if (ai - di >= 0 && aj - dj >= 0 && aj - dj <= 3)
                        continue;                       // compile-time prune
                    float pa = Wn[ai + 2][aj + 2];
                    float pb = Wn[ai + 2 - di][aj + 2 - dj];
                    float d = pb - pa;
                    float w = __builtin_amdgcn_exp2f(fmaf(d * coef2, d, cs));
                    num[ai][aj] = fmaf(w, pb, num[ai][aj]);
                    den[ai][aj] += w;
                }
            }
        }
    }

#pragma unroll
    for (int ai = 0; ai < 4; ++ai) {
        float4 o;
        o.x = num[ai][0] * __builtin_amdgcn_rcpf(den[ai][0]);
        o.y = num[ai][1] * __builtin_amdgcn_rcpf(den[ai][1]);
        o.z = num[ai][2] * __builtin_amdgcn_rcpf(den[ai][2]);
        o.w = num[ai][3] * __builtin_amdgcn_rcpf(den[ai][3]);
        *(float4*)(oplane + (h0 + ai) * W_ + w0) = o;
    }
}

extern "C" void kernel_launch(void* const* d_in, const int* in_sizes, int n_in,
                              void* d_out, int out_size, void* d_ws, size_t ws_size,
                              hipStream_t stream)
{
    const float* x = (const float*)d_in[0];
    float* out = (float*)d_out;
    int nthreads = in_sizes[0] >> 4;         // 16 px per thread
    int blocks = (nthreads + 255) / 256;
    bilateral_kernel<<<blocks, 256, 0, stream>>>(x, out, nthreads);
}